// Round 2
// baseline (391.359 us; speedup 1.0000x reference)
//
#include <hip/hip_runtime.h>
#include <stdint.h>

// EmbraceNet selection: M=4, B=2048, C=8192.
// out[b,c] = x[idx[b,c], b, c],  idx = argmax_m(first-wins) of
// jax threefry2x32 partitionable bits (out0^out1) >> 9 at counter (0, (b*C+c)*4+m).
// Scheme confirmed bit-exact (round 1: absmax = 0.0).
//
// This round: 4 outputs/thread, float4 coalesced loads of ALL 4 planes +
// in-register cndmask select (replaces the divergent per-lane gather;
// identical HBM traffic since ~99% of lines are touched anyway).

constexpr uint32_t kBC   = 2048u * 8192u;   // 2^24 outputs
constexpr uint32_t kKey1 = 0u;              // jax.random.key(42) -> [0, 42]
constexpr uint32_t kKey2 = 42u;

__device__ __forceinline__ uint32_t rotl32(uint32_t x, uint32_t d) {
  return (x << d) | (x >> (32u - d));
}

// threefry2x32, key (0,42), counter (0, ctr_lo); partitionable bits = x0 ^ x1.
__device__ __forceinline__ uint32_t tf_bits(uint32_t ctr_lo) {
  const uint32_t ks0 = kKey1;
  const uint32_t ks1 = kKey2;
  const uint32_t ks2 = 0x1BD11BDAu ^ kKey1 ^ kKey2;
  uint32_t x0 = ks0;             // ctr_hi = 0
  uint32_t x1 = ctr_lo + ks1;
#define TF_R(r) { x0 += x1; x1 = rotl32(x1, r); x1 ^= x0; }
  TF_R(13u) TF_R(15u) TF_R(26u) TF_R(6u)
  x0 += ks1; x1 += ks2 + 1u;
  TF_R(17u) TF_R(29u) TF_R(16u) TF_R(24u)
  x0 += ks2; x1 += ks0 + 2u;
  TF_R(13u) TF_R(15u) TF_R(26u) TF_R(6u)
  x0 += ks0; x1 += ks1 + 3u;
  TF_R(17u) TF_R(29u) TF_R(16u) TF_R(24u)
  x0 += ks1; x1 += ks2 + 4u;
  TF_R(13u) TF_R(15u) TF_R(26u) TF_R(6u)
  x0 += ks2; x1 += ks0 + 5u;
#undef TF_R
  return x0 ^ x1;
}

__global__ __launch_bounds__(256) void embrace_kernel(const float4* __restrict__ x4,
                                                      float4* __restrict__ out4) {
  uint32_t t = blockIdx.x * 256u + threadIdx.x;   // handles outputs 4t .. 4t+3
  constexpr uint32_t kQ = kBC / 4u;               // float4 elements per plane

  // Coalesced loads of all 4 planes — issued first so latency hides under hashes.
  float4 v0 = x4[0u * kQ + t];
  float4 v1 = x4[1u * kQ + t];
  float4 v2 = x4[2u * kQ + t];
  float4 v3 = x4[3u * kQ + t];

  uint32_t jb = t * 16u;   // 16 gumbel counters for these 4 outputs
  float r[4];
  const float* p0 = &v0.x; const float* p1 = &v1.x;
  const float* p2 = &v2.x; const float* p3 = &v3.x;

#pragma unroll
  for (uint32_t i = 0; i < 4u; ++i) {
    uint32_t f0 = tf_bits(jb + i * 4u + 0u) >> 9;
    uint32_t f1 = tf_bits(jb + i * 4u + 1u) >> 9;
    uint32_t f2 = tf_bits(jb + i * 4u + 2u) >> 9;
    uint32_t f3 = tf_bits(jb + i * 4u + 3u) >> 9;
    // argmax first-wins: strict '>' replaces only on greater.
    uint32_t best = f0; float val = p0[i];
    if (f1 > best) { best = f1; val = p1[i]; }
    if (f2 > best) { best = f2; val = p2[i]; }
    if (f3 > best) { best = f3; val = p3[i]; }
    r[i] = val;
  }

  out4[t] = make_float4(r[0], r[1], r[2], r[3]);
}

extern "C" void kernel_launch(void* const* d_in, const int* in_sizes, int n_in,
                              void* d_out, int out_size, void* d_ws, size_t ws_size,
                              hipStream_t stream) {
  const float4* x4 = (const float4*)d_in[0];
  float4* out4 = (float4*)d_out;
  (void)in_sizes; (void)n_in; (void)out_size; (void)d_ws; (void)ws_size;
  embrace_kernel<<<dim3(kBC / 4u / 256u), dim3(256u), 0, stream>>>(x4, out4);
}

// Round 3
// 390.682 us; speedup vs baseline: 1.0017x; 1.0017x over previous
//
#include <hip/hip_runtime.h>
#include <stdint.h>

// EmbraceNet selection: M=4, B=2048, C=8192.
// out[b,c] = x[idx[b,c], b, c],  idx = argmax_m(first-wins) of
// jax threefry2x32 partitionable bits (out0^out1) >> 9 at counter (0, (b*C+c)*4+m).
// Scheme confirmed bit-exact (rounds 1-2: absmax = 0.0).
//
// Round 3: force 1-instruction rotates via v_alignbit_b32
// (rotl(x,d) == alignbit(x,x,32-d)) — if the compiler was lowering the
// shift-or rotate as 3 VALU ops, each threefry round was 5 ops instead of 3
// and this cuts the hash cost ~40%.

constexpr uint32_t kBC   = 2048u * 8192u;   // 2^24 outputs
constexpr uint32_t kKey1 = 0u;              // jax.random.key(42) -> [0, 42]
constexpr uint32_t kKey2 = 42u;

__device__ __forceinline__ uint32_t rotl32(uint32_t x, uint32_t d) {
  // v_alignbit_b32 dst, s0, s1, s2  ==  ((u64(s0)<<32 | s1) >> s2)[31:0]
  // rotl(x,d) = alignbit(x, x, 32-d)  — single VALU instruction, guaranteed.
  return __builtin_amdgcn_alignbit(x, x, 32u - d);
}

// threefry2x32, key (0,42), counter (0, ctr_lo); partitionable bits = x0 ^ x1.
__device__ __forceinline__ uint32_t tf_bits(uint32_t ctr_lo) {
  const uint32_t ks0 = kKey1;
  const uint32_t ks1 = kKey2;
  const uint32_t ks2 = 0x1BD11BDAu ^ kKey1 ^ kKey2;
  uint32_t x0 = ks0;             // ctr_hi = 0
  uint32_t x1 = ctr_lo + ks1;
#define TF_R(r) { x0 += x1; x1 = rotl32(x1, r); x1 ^= x0; }
  TF_R(13u) TF_R(15u) TF_R(26u) TF_R(6u)
  x0 += ks1; x1 += ks2 + 1u;
  TF_R(17u) TF_R(29u) TF_R(16u) TF_R(24u)
  x0 += ks2; x1 += ks0 + 2u;
  TF_R(13u) TF_R(15u) TF_R(26u) TF_R(6u)
  x0 += ks0; x1 += ks1 + 3u;
  TF_R(17u) TF_R(29u) TF_R(16u) TF_R(24u)
  x0 += ks1; x1 += ks2 + 4u;
  TF_R(13u) TF_R(15u) TF_R(26u) TF_R(6u)
  x0 += ks2; x1 += ks0 + 5u;
#undef TF_R
  return x0 ^ x1;
}

__global__ __launch_bounds__(256) void embrace_kernel(const float4* __restrict__ x4,
                                                      float4* __restrict__ out4) {
  uint32_t t = blockIdx.x * 256u + threadIdx.x;   // handles outputs 4t .. 4t+3
  constexpr uint32_t kQ = kBC / 4u;               // float4 elements per plane

  // Coalesced loads of all 4 planes — issued first so latency hides under hashes.
  float4 v0 = x4[0u * kQ + t];
  float4 v1 = x4[1u * kQ + t];
  float4 v2 = x4[2u * kQ + t];
  float4 v3 = x4[3u * kQ + t];

  uint32_t jb = t * 16u;   // 16 gumbel counters for these 4 outputs
  float r[4];
  const float* p0 = &v0.x; const float* p1 = &v1.x;
  const float* p2 = &v2.x; const float* p3 = &v3.x;

#pragma unroll
  for (uint32_t i = 0; i < 4u; ++i) {
    uint32_t f0 = tf_bits(jb + i * 4u + 0u) >> 9;
    uint32_t f1 = tf_bits(jb + i * 4u + 1u) >> 9;
    uint32_t f2 = tf_bits(jb + i * 4u + 2u) >> 9;
    uint32_t f3 = tf_bits(jb + i * 4u + 3u) >> 9;
    // argmax first-wins: strict '>' replaces only on greater.
    uint32_t best = f0; float val = p0[i];
    if (f1 > best) { best = f1; val = p1[i]; }
    if (f2 > best) { best = f2; val = p2[i]; }
    if (f3 > best) { best = f3; val = p3[i]; }
    r[i] = val;
  }

  out4[t] = make_float4(r[0], r[1], r[2], r[3]);
}

extern "C" void kernel_launch(void* const* d_in, const int* in_sizes, int n_in,
                              void* d_out, int out_size, void* d_ws, size_t ws_size,
                              hipStream_t stream) {
  const float4* x4 = (const float4*)d_in[0];
  float4* out4 = (float4*)d_out;
  (void)in_sizes; (void)n_in; (void)out_size; (void)d_ws; (void)ws_size;
  embrace_kernel<<<dim3(kBC / 4u / 256u), dim3(256u), 0, stream>>>(x4, out4);
}